// Round 1
// baseline (8902.104 us; speedup 1.0000x reference)
//
#include <hip/hip_runtime.h>
#include <hip/hip_bf16.h>
#include <stdint.h>

#define B_ 8
#define L_ 512
#define H_ 768
#define WW_ 12
#define C_ 25
#define S_ (L_*WW_)   // 6144
#define HH 384        // H/2
#define G4 1536       // 4*HH

using bf16x8 = __attribute__((ext_vector_type(8))) short;
using f32x4  = __attribute__((ext_vector_type(4))) float;

static __device__ __forceinline__ unsigned short f2bf(float x){
  unsigned u = __float_as_uint(x);
  unsigned r = (u + 0x7FFFu + ((u >> 16) & 1u)) >> 16;
  return (unsigned short)r;
}
static __device__ __forceinline__ float bflo(unsigned u){ return __uint_as_float(u << 16); }
static __device__ __forceinline__ float bfhi(unsigned u){ return __uint_as_float(u & 0xFFFF0000u); }

static __device__ __forceinline__ float sigmoid_f(float x){
  x = fminf(15.f, fmaxf(-15.f, x));
  return 1.f / (1.f + __expf(-x));
}
static __device__ __forceinline__ float tanh_f(float x){
  x = fminf(15.f, fmaxf(-15.f, x));
  float e = __expf(-2.f * x);
  return (1.f - e) / (1.f + e);
}
static __device__ __forceinline__ unsigned relu2(unsigned u){
  if (u & 0x80000000u) u &= 0x0000FFFFu;   // hi bf16 negative -> zero hi half
  if (u & 0x00008000u) u &= 0xFFFF0000u;   // lo bf16 negative -> zero lo half
  return u;
}

// ---------------- fp32 -> bf16 cast (n multiple of 4) ----------------
__global__ void k_cast_bf16(const float* __restrict__ s, unsigned short* __restrict__ d, long n4){
  long i = (long)blockIdx.x * blockDim.x + threadIdx.x;
  if (i >= n4) return;
  float4 v = reinterpret_cast<const float4*>(s)[i];
  ushort4 o;
  o.x = f2bf(v.x); o.y = f2bf(v.y); o.z = f2bf(v.z); o.w = f2bf(v.w);
  reinterpret_cast<ushort4*>(d)[i] = o;
}

__global__ void k_biascomb(const float* __restrict__ a, const float* __restrict__ b,
                           float* __restrict__ o, int n){
  int i = blockIdx.x * blockDim.x + threadIdx.x;
  if (i < n) o[i] = a[i] + b[i];
}

// Pack W_hh [1536][384] fp32 -> [96][768] uint4 of bf16 pairs.
// Element (c,t): x={W[t][4c],W[t][4c+1]}, y={W[t][4c+2],W[t][4c+3]},
//                z,w = same for row t+768.
__global__ void k_wpack(const float* __restrict__ whh, uint4* __restrict__ wp, int dirbase){
  int i = blockIdx.x * blockDim.x + threadIdx.x;
  if (i >= 96 * 768) return;
  int c = i / 768, t = i % 768;
  const float* R0 = whh + (size_t)t * HH + 4 * c;
  const float* R1 = whh + (size_t)(t + 768) * HH + 4 * c;
  uint4 o;
  o.x = (unsigned)f2bf(R0[0]) | ((unsigned)f2bf(R0[1]) << 16);
  o.y = (unsigned)f2bf(R0[2]) | ((unsigned)f2bf(R0[3]) << 16);
  o.z = (unsigned)f2bf(R1[0]) | ((unsigned)f2bf(R1[1]) << 16);
  o.w = (unsigned)f2bf(R1[2]) | ((unsigned)f2bf(R1[3]) << 16);
  wp[dirbase + i] = o;
}

// ---------------- generic NT GEMM: C[M,N] = act(A[M,K] @ B[N,K]^T + bias) ----
// A,B bf16 (K-contiguous). ACT: 0=none 1=relu. OUTBF: 0=fp32 out, 1=bf16 out.
// Block 256 thr = 4 waves (2x2), 128x128 tile; wave = 64x64 via 4x4 frags.
template<int ACT, int OUTBF>
__global__ __launch_bounds__(256) void k_gemm_nt(
    const unsigned short* __restrict__ A, const unsigned short* __restrict__ Bm,
    const float* __restrict__ bias, void* __restrict__ Cout,
    int M, int N, int K)
{
  const int lane = threadIdx.x & 63;
  const int wave = threadIdx.x >> 6;
  const int wr = wave >> 1, wc = wave & 1;
  const int l16 = lane & 15, lq = lane >> 4;
  const int m0 = blockIdx.y * 128 + wr * 64;
  const int n0 = blockIdx.x * 128 + wc * 64;

  f32x4 acc[4][4];
  #pragma unroll
  for (int a = 0; a < 4; a++)
    #pragma unroll
    for (int b = 0; b < 4; b++)
      acc[a][b] = (f32x4)0.f;

  const unsigned short* Ap[4]; bool am[4];
  #pragma unroll
  for (int mi = 0; mi < 4; mi++){
    int row = m0 + mi * 16 + l16;
    am[mi] = row < M;
    int rc = am[mi] ? row : 0;
    Ap[mi] = A + (size_t)rc * K + lq * 8;
  }
  const unsigned short* Bp[4];
  #pragma unroll
  for (int ni = 0; ni < 4; ni++){
    int col = n0 + ni * 16 + l16;   // N is always a multiple of 128
    Bp[ni] = Bm + (size_t)col * K + lq * 8;
  }

  for (int k = 0; k < K; k += 32){
    bf16x8 af[4], bfr[4];
    #pragma unroll
    for (int mi = 0; mi < 4; mi++){
      bf16x8 v = {0,0,0,0,0,0,0,0};
      if (am[mi]) v = *reinterpret_cast<const bf16x8*>(Ap[mi] + k);
      af[mi] = v;
    }
    #pragma unroll
    for (int ni = 0; ni < 4; ni++)
      bfr[ni] = *reinterpret_cast<const bf16x8*>(Bp[ni] + k);
    #pragma unroll
    for (int mi = 0; mi < 4; mi++)
      #pragma unroll
      for (int ni = 0; ni < 4; ni++)
        acc[mi][ni] = __builtin_amdgcn_mfma_f32_16x16x32_bf16(af[mi], bfr[ni], acc[mi][ni], 0, 0, 0);
  }

  #pragma unroll
  for (int mi = 0; mi < 4; mi++){
    #pragma unroll
    for (int r = 0; r < 4; r++){
      int row = m0 + mi * 16 + lq * 4 + r;
      if (row >= M) continue;
      #pragma unroll
      for (int ni = 0; ni < 4; ni++){
        int col = n0 + ni * 16 + l16;
        float v = acc[mi][ni][r] + bias[col];
        if (ACT) v = v > 0.f ? v : 0.f;
        if (OUTBF) ((unsigned short*)Cout)[(size_t)row * N + col] = f2bf(v);
        else       ((float*)Cout)[(size_t)row * N + col] = v;
      }
    }
  }
}

// ---------------- LSTM recurrence ----------------
// grid 16 = (b, dir); block 768. Thread t computes gate rows t and t+768.
// xg already includes b_ih + b_hh. hseq[b,t, dir*384 + j] = h_j * mask.
__global__ __launch_bounds__(768) void k_lstm(
    const float* __restrict__ xgf, const float* __restrict__ xgb,
    const uint4* __restrict__ Wp, const int* __restrict__ mask,
    float* __restrict__ hseq)
{
  const int b = blockIdx.x & 7;
  const int dir = blockIdx.x >> 3;
  const int t = threadIdx.x;
  const float* xg = dir ? xgb : xgf;
  const uint4* wp = Wp + (size_t)dir * 96 * 768 + t;

  __shared__ alignas(16) float h_s[HH];
  __shared__ float gs[G4];

  float c_reg = 0.f;
  if (t < HH) h_s[t] = 0.f;
  __syncthreads();

  for (int s = 0; s < L_; s++){
    int tt = dir ? (L_ - 1 - s) : s;
    const float* xr = xg + (size_t)(b * L_ + tt) * G4;
    float a0 = xr[t], a1 = xr[t + 768];
    const float4* h4 = reinterpret_cast<const float4*>(h_s);
    #pragma unroll 8
    for (int c = 0; c < 96; c++){
      uint4 w = wp[(size_t)c * 768];
      float4 hv = h4[c];
      a0 += bflo(w.x) * hv.x + bfhi(w.x) * hv.y + bflo(w.y) * hv.z + bfhi(w.y) * hv.w;
      a1 += bflo(w.z) * hv.x + bfhi(w.z) * hv.y + bflo(w.w) * hv.z + bfhi(w.w) * hv.w;
    }
    gs[t] = a0;
    gs[t + 768] = a1;
    __syncthreads();
    if (t < HH){
      float gi = gs[t], gf = gs[HH + t], gg = gs[2 * HH + t], go = gs[3 * HH + t];
      c_reg = sigmoid_f(gf) * c_reg + sigmoid_f(gi) * tanh_f(gg);
      float h = sigmoid_f(go) * tanh_f(c_reg);
      h_s[t] = h;
      float mv = (float)mask[b * L_ + tt];
      hseq[(size_t)(b * L_ + tt) * H_ + dir * HH + t] = h * mv;
    }
    __syncthreads();
  }
}

// ---------------- gather + concat + relu (per batch) ----------------
// cat[s, 0:768] = relu(srep[b, i0(s), :]); cat[s, 768:1536] = relu(erep[b, i1(s), :])
__global__ void k_gather(const unsigned short* __restrict__ srep,
                         const unsigned short* __restrict__ erep,
                         const int* __restrict__ sidx, int b,
                         uint4* __restrict__ cat)
{
  int i = blockIdx.x * blockDim.x + threadIdx.x;  // s*192 + c
  if (i >= S_ * 192) return;
  int s = i / 192, c = i % 192;
  int i0 = sidx[(size_t)(b * S_ + s) * 2 + 0];
  int i1 = sidx[(size_t)(b * S_ + s) * 2 + 1];
  i0 = min(max(i0, 0), L_ - 1);
  i1 = min(max(i1, 0), L_ - 1);
  uint4 v;
  if (c < 96)
    v = reinterpret_cast<const uint4*>(srep + (size_t)(b * L_ + i0) * H_)[c];
  else
    v = reinterpret_cast<const uint4*>(erep + (size_t)(b * L_ + i1) * H_)[c - 96];
  v.x = relu2(v.x); v.y = relu2(v.y); v.z = relu2(v.z); v.w = relu2(v.w);
  cat[i] = v;
}

extern "C" void kernel_launch(void* const* d_in, const int* in_sizes, int n_in,
                              void* d_out, int out_size, void* d_ws, size_t ws_size,
                              hipStream_t stream)
{
  (void)in_sizes; (void)n_in; (void)out_size; (void)ws_size;
  const float* we     = (const float*)d_in[0];
  const int*   mask   = (const int*)  d_in[1];
  const int*   sidx   = (const int*)  d_in[2];
  const float* pe     = (const float*)d_in[3];
  const float* w_ih_f = (const float*)d_in[4];
  const float* w_hh_f = (const float*)d_in[5];
  const float* b_ih_f = (const float*)d_in[6];
  const float* b_hh_f = (const float*)d_in[7];
  const float* w_ih_b = (const float*)d_in[8];
  const float* w_hh_b = (const float*)d_in[9];
  const float* b_ih_b = (const float*)d_in[10];
  const float* b_hh_b = (const float*)d_in[11];
  const float* sw1 = (const float*)d_in[12]; const float* sb1 = (const float*)d_in[13];
  const float* sw2 = (const float*)d_in[14]; const float* sb2 = (const float*)d_in[15];
  const float* ew1 = (const float*)d_in[16]; const float* eb1 = (const float*)d_in[17];
  const float* ew2 = (const float*)d_in[18]; const float* eb2 = (const float*)d_in[19];
  const float* ow1 = (const float*)d_in[20]; const float* ob1 = (const float*)d_in[21];
  const float* ow2 = (const float*)d_in[22]; const float* ob2 = (const float*)d_in[23];
  const float* pw1 = (const float*)d_in[24]; const float* pb1 = (const float*)d_in[25];
  const float* pw2 = (const float*)d_in[26]; const float* pb2 = (const float*)d_in[27];

  char* wsp = (char*)d_ws; size_t off = 0;
  auto alloc = [&](size_t bytes) -> void* {
    void* p = wsp + off;
    off += (bytes + 255) & ~(size_t)255;
    return p;
  };

  unsigned short* we_bf   = (unsigned short*)alloc((size_t)4096*768*2);
  unsigned short* wihf_bf = (unsigned short*)alloc((size_t)1536*768*2);
  unsigned short* wihb_bf = (unsigned short*)alloc((size_t)1536*768*2);
  float* bc_f = (float*)alloc((size_t)1536*4);
  float* bc_b = (float*)alloc((size_t)1536*4);
  float* xg_f = (float*)alloc((size_t)4096*1536*4);
  float* xg_b = (float*)alloc((size_t)4096*1536*4);
  uint4* wpk  = (uint4*)alloc((size_t)2*96*768*16);
  float* hseq = (float*)alloc((size_t)4096*768*4);
  unsigned short* h_bf  = (unsigned short*)alloc((size_t)4096*768*2);
  unsigned short* sw1b  = (unsigned short*)alloc((size_t)3072*768*2);
  unsigned short* sw2b  = (unsigned short*)alloc((size_t)768*3072*2);
  unsigned short* ew1b  = (unsigned short*)alloc((size_t)3072*768*2);
  unsigned short* ew2b  = (unsigned short*)alloc((size_t)768*3072*2);
  unsigned short* ow1b  = (unsigned short*)alloc((size_t)3072*1536*2);
  unsigned short* ow2b  = (unsigned short*)alloc((size_t)768*3072*2);
  unsigned short* pw1b  = (unsigned short*)alloc((size_t)3072*768*2);
  unsigned short* pw2b  = (unsigned short*)alloc((size_t)768*3072*2);
  unsigned short* srep  = (unsigned short*)alloc((size_t)4096*768*2);
  unsigned short* erep  = (unsigned short*)alloc((size_t)4096*768*2);
  unsigned short* midb  = (unsigned short*)alloc((size_t)6144*3072*2);
  unsigned short* catb  = (unsigned short*)alloc((size_t)6144*1536*2);
  unsigned short* pe_bf = (unsigned short*)alloc((size_t)200*768*2);
  unsigned short* pmid  = (unsigned short*)alloc((size_t)200*3072*2);

  auto cast = [&](const float* s, unsigned short* d, size_t n){
    long n4 = (long)(n / 4);
    int grid = (int)((n4 + 255) / 256);
    k_cast_bf16<<<grid, 256, 0, stream>>>(s, d, n4);
  };

  cast(we, we_bf, (size_t)4096*768);
  cast(w_ih_f, wihf_bf, (size_t)1536*768);
  cast(w_ih_b, wihb_bf, (size_t)1536*768);
  cast(sw1, sw1b, (size_t)3072*768);  cast(sw2, sw2b, (size_t)768*3072);
  cast(ew1, ew1b, (size_t)3072*768);  cast(ew2, ew2b, (size_t)768*3072);
  cast(ow1, ow1b, (size_t)3072*1536); cast(ow2, ow2b, (size_t)768*3072);
  cast(pw1, pw1b, (size_t)3072*768);  cast(pw2, pw2b, (size_t)768*3072);
  cast(pe, pe_bf, (size_t)200*768);

  k_biascomb<<<6, 256, 0, stream>>>(b_ih_f, b_hh_f, bc_f, 1536);
  k_biascomb<<<6, 256, 0, stream>>>(b_ih_b, b_hh_b, bc_b, 1536);
  k_wpack<<<(96*768)/256, 256, 0, stream>>>(w_hh_f, wpk, 0);
  k_wpack<<<(96*768)/256, 256, 0, stream>>>(w_hh_b, wpk, 96*768);

  dim3 blk(256);
  // input-gate precompute (both biases folded in)
  k_gemm_nt<0,0><<<dim3(1536/128, 4096/128), blk, 0, stream>>>(we_bf, wihf_bf, bc_f, xg_f, 4096, 1536, 768);
  k_gemm_nt<0,0><<<dim3(1536/128, 4096/128), blk, 0, stream>>>(we_bf, wihb_bf, bc_b, xg_b, 4096, 1536, 768);

  k_lstm<<<16, 768, 0, stream>>>(xg_f, xg_b, wpk, mask, hseq);
  cast(hseq, h_bf, (size_t)4096*768);

  // start / end MLPs (bf16 chain)
  k_gemm_nt<1,1><<<dim3(3072/128, 4096/128), blk, 0, stream>>>(h_bf, sw1b, sb1, midb, 4096, 3072, 768);
  k_gemm_nt<0,1><<<dim3( 768/128, 4096/128), blk, 0, stream>>>(midb, sw2b, sb2, srep, 4096,  768, 3072);
  k_gemm_nt<1,1><<<dim3(3072/128, 4096/128), blk, 0, stream>>>(h_bf, ew1b, eb1, midb, 4096, 3072, 768);
  k_gemm_nt<0,1><<<dim3( 768/128, 4096/128), blk, 0, stream>>>(midb, ew2b, eb2, erep, 4096,  768, 3072);

  float* outp = (float*)d_out;
  for (int b = 0; b < 8; b++){
    k_gather<<<(S_*192)/256, 256, 0, stream>>>(srep, erep, sidx, b, (uint4*)catb);
    k_gemm_nt<1,1><<<dim3(3072/128, 6144/128), blk, 0, stream>>>(catb, ow1b, ob1, midb, 6144, 3072, 1536);
    k_gemm_nt<0,0><<<dim3( 768/128, 6144/128), blk, 0, stream>>>(midb, ow2b, ob2,
                                                                 outp + (size_t)b * S_ * H_, 6144, 768, 3072);
  }

  // prompt projection
  k_gemm_nt<1,1><<<dim3(3072/128, 2), blk, 0, stream>>>(pe_bf, pw1b, pb1, pmid, 200, 3072, 768);
  k_gemm_nt<0,0><<<dim3( 768/128, 2), blk, 0, stream>>>(pmid, pw2b, pb2,
                                                        outp + (size_t)37748736, 200, 768, 3072);
}

// Round 2
// 7457.132 us; speedup vs baseline: 1.1938x; 1.1938x over previous
//
#include <hip/hip_runtime.h>
#include <hip/hip_bf16.h>
#include <stdint.h>

#define B_ 8
#define L_ 512
#define H_ 768
#define WW_ 12
#define C_ 25
#define S_ (L_*WW_)   // 6144
#define HH 384        // H/2
#define G4 1536       // 4*HH

using bf16x8 = __attribute__((ext_vector_type(8))) short;
using f32x4  = __attribute__((ext_vector_type(4))) float;

static __device__ __forceinline__ unsigned short f2bf(float x){
  unsigned u = __float_as_uint(x);
  unsigned r = (u + 0x7FFFu + ((u >> 16) & 1u)) >> 16;
  return (unsigned short)r;
}

static __device__ __forceinline__ float sigmoid_f(float x){
  x = fminf(15.f, fmaxf(-15.f, x));
  return 1.f / (1.f + __expf(-x));
}
static __device__ __forceinline__ float tanh_f(float x){
  x = fminf(15.f, fmaxf(-15.f, x));
  float e = __expf(-2.f * x);
  return (1.f - e) / (1.f + e);
}
static __device__ __forceinline__ unsigned relu2(unsigned u){
  if (u & 0x80000000u) u &= 0x0000FFFFu;
  if (u & 0x00008000u) u &= 0xFFFF0000u;
  return u;
}

// ---------------- fp32 -> bf16 cast (n multiple of 4) ----------------
__global__ void k_cast_bf16(const float* __restrict__ s, unsigned short* __restrict__ d, long n4){
  long i = (long)blockIdx.x * blockDim.x + threadIdx.x;
  if (i >= n4) return;
  float4 v = reinterpret_cast<const float4*>(s)[i];
  ushort4 o;
  o.x = f2bf(v.x); o.y = f2bf(v.y); o.z = f2bf(v.z); o.w = f2bf(v.w);
  reinterpret_cast<ushort4*>(d)[i] = o;
}

__global__ void k_biascomb(const float* __restrict__ a, const float* __restrict__ b,
                           float* __restrict__ o, int n){
  int i = blockIdx.x * blockDim.x + threadIdx.x;
  if (i < n) o[i] = a[i] + b[i];
}

// ---------------- generic NT GEMM: C[M,N] = act(A[M,K] @ B[N,K]^T + bias) ----
template<int ACT, int OUTBF>
__global__ __launch_bounds__(256) void k_gemm_nt(
    const unsigned short* __restrict__ A, const unsigned short* __restrict__ Bm,
    const float* __restrict__ bias, void* __restrict__ Cout,
    int M, int N, int K)
{
  const int lane = threadIdx.x & 63;
  const int wave = threadIdx.x >> 6;
  const int wr = wave >> 1, wc = wave & 1;
  const int l16 = lane & 15, lq = lane >> 4;
  const int m0 = blockIdx.y * 128 + wr * 64;
  const int n0 = blockIdx.x * 128 + wc * 64;

  f32x4 acc[4][4];
  #pragma unroll
  for (int a = 0; a < 4; a++)
    #pragma unroll
    for (int b = 0; b < 4; b++)
      acc[a][b] = (f32x4)0.f;

  const unsigned short* Ap[4]; bool am[4];
  #pragma unroll
  for (int mi = 0; mi < 4; mi++){
    int row = m0 + mi * 16 + l16;
    am[mi] = row < M;
    int rc = am[mi] ? row : 0;
    Ap[mi] = A + (size_t)rc * K + lq * 8;
  }
  const unsigned short* Bp[4];
  #pragma unroll
  for (int ni = 0; ni < 4; ni++){
    int col = n0 + ni * 16 + l16;
    Bp[ni] = Bm + (size_t)col * K + lq * 8;
  }

  for (int k = 0; k < K; k += 32){
    bf16x8 af[4], bfr[4];
    #pragma unroll
    for (int mi = 0; mi < 4; mi++){
      bf16x8 v = {0,0,0,0,0,0,0,0};
      if (am[mi]) v = *reinterpret_cast<const bf16x8*>(Ap[mi] + k);
      af[mi] = v;
    }
    #pragma unroll
    for (int ni = 0; ni < 4; ni++)
      bfr[ni] = *reinterpret_cast<const bf16x8*>(Bp[ni] + k);
    #pragma unroll
    for (int mi = 0; mi < 4; mi++)
      #pragma unroll
      for (int ni = 0; ni < 4; ni++)
        acc[mi][ni] = __builtin_amdgcn_mfma_f32_16x16x32_bf16(af[mi], bfr[ni], acc[mi][ni], 0, 0, 0);
  }

  #pragma unroll
  for (int mi = 0; mi < 4; mi++){
    #pragma unroll
    for (int r = 0; r < 4; r++){
      int row = m0 + mi * 16 + lq * 4 + r;
      if (row >= M) continue;
      #pragma unroll
      for (int ni = 0; ni < 4; ni++){
        int col = n0 + ni * 16 + l16;
        float v = acc[mi][ni][r] + bias[col];
        if (ACT) v = v > 0.f ? v : 0.f;
        if (OUTBF) ((unsigned short*)Cout)[(size_t)row * N + col] = f2bf(v);
        else       ((float*)Cout)[(size_t)row * N + col] = v;
      }
    }
  }
}

// ---------------- distributed LSTM recurrence ----------------
// 64 blocks = dir(2) x slice(32). Block owns 12 hidden units (4 gates each),
// W_hh slice resident in registers as MFMA B-frags (wave = gate).
// Per step: gates[8 batch][4x12] via MFMA on h (bf16, LDS, XOR-swizzled),
// nonlinearity on 96 threads, h-slice exchanged via global parity buffers +
// device-scope flag sync.
__global__ __launch_bounds__(256) void k_lstm2(
    const float* __restrict__ xgf, const float* __restrict__ xgb,
    const unsigned short* __restrict__ Wbf,   // [2][1536][384] bf16
    const int* __restrict__ mask,
    unsigned short* __restrict__ hbf,         // [4096][768] bf16 out (masked)
    unsigned short* __restrict__ hglob,       // [2 dir][2 par][8*384] bf16
    int* __restrict__ flags)                  // [2][32], zeroed before launch
{
  const int dir = blockIdx.x >> 5;
  const int sl  = blockIdx.x & 31;
  const int j0  = sl * 12;
  const int tid = threadIdx.x;
  const int lane = tid & 63;
  const int w = tid >> 6;          // wave index == gate (i,f,g,o)
  const int l16 = lane & 15, lq = lane >> 4;

  __shared__ alignas(16) unsigned short hls[8 * HH];  // 6 KB, XOR-swizzled
  __shared__ float gsl[4][8][16];

  const float* xg = dir ? xgb : xgf;
  const unsigned short* Wg = Wbf + (size_t)dir * G4 * HH;

  // resident W_hh B-fragments: rows = gate w, hidden j0+l16 (clamped), K=384
  bf16x8 bfr[12];
  {
    int jr = l16 < 12 ? l16 : 11;
    const unsigned short* wr_ = Wg + ((size_t)w * HH + j0 + jr) * HH + lq * 8;
    #pragma unroll
    for (int kf = 0; kf < 12; kf++)
      bfr[kf] = *reinterpret_cast<const bf16x8*>(wr_ + kf * 32);
  }

  for (int i = tid; i < 8 * HH; i += 256) hls[i] = 0;

  const int cb = tid / 12, cj = tid - cb * 12;   // valid when tid<96
  const bool comb = tid < 96;
  const int jg = j0 + cj;
  float c_state = 0.f;

  unsigned short* hgl0 = hglob + ((size_t)dir * 2 + 0) * (8 * HH);
  unsigned short* hgl1 = hglob + ((size_t)dir * 2 + 1) * (8 * HH);
  int* myflags = flags + dir * 32;

  __syncthreads();

  for (int s = 0; s < L_; s++){
    const int t = dir ? (L_ - 1 - s) : s;

    // prefetch xg + mask for combine phase (hides HBM latency under MFMA)
    float xi = 0.f, xf = 0.f, xgg = 0.f, xo = 0.f; int mv = 0;
    if (comb){
      const float* xr = xg + ((size_t)cb * L_ + t) * G4;
      xi  = xr[jg];
      xf  = xr[HH + jg];
      xgg = xr[2 * HH + jg];
      xo  = xr[3 * HH + jg];
      mv  = mask[cb * L_ + t];
    }

    // gates = h @ Wslice^T  (M=16 rows, 8 valid batches; N=16 cols, 12 valid j)
    f32x4 acc0 = (f32x4)0.f, acc1 = (f32x4)0.f;
    const int arow = l16 & 7;
    #pragma unroll
    for (int kf = 0; kf < 12; kf += 2){
      int by0 = (arow * 768 + kf * 64 + lq * 16) ^ (arow << 4);
      int by1 = (arow * 768 + (kf + 1) * 64 + lq * 16) ^ (arow << 4);
      bf16x8 a0 = *reinterpret_cast<const bf16x8*>((const char*)hls + by0);
      bf16x8 a1 = *reinterpret_cast<const bf16x8*>((const char*)hls + by1);
      acc0 = __builtin_amdgcn_mfma_f32_16x16x32_bf16(a0, bfr[kf],     acc0, 0, 0, 0);
      acc1 = __builtin_amdgcn_mfma_f32_16x16x32_bf16(a1, bfr[kf + 1], acc1, 0, 0, 0);
    }
    if (lq < 2){
      #pragma unroll
      for (int r = 0; r < 4; r++)
        gsl[w][lq * 4 + r][l16] = acc0[r] + acc1[r];
    }
    __syncthreads();

    if (comb){
      float gi = gsl[0][cb][cj] + xi;
      float gf = gsl[1][cb][cj] + xf;
      float gg = gsl[2][cb][cj] + xgg;
      float go = gsl[3][cb][cj] + xo;
      c_state = sigmoid_f(gf) * c_state + sigmoid_f(gi) * tanh_f(gg);
      float h = sigmoid_f(go) * tanh_f(c_state);
      (s & 1 ? hgl1 : hgl0)[cb * HH + jg] = f2bf(h);
      hbf[((size_t)cb * L_ + t) * H_ + dir * HH + jg] = f2bf(h * (float)mv);
      __threadfence();
    }
    __syncthreads();
    if (tid == 0){
      __threadfence();
      __hip_atomic_store(&myflags[sl], s + 1, __ATOMIC_RELEASE, __HIP_MEMORY_SCOPE_AGENT);
    }

    if (s < L_ - 1){
      if (tid < 32){
        while (__hip_atomic_load(&myflags[tid], __ATOMIC_ACQUIRE, __HIP_MEMORY_SCOPE_AGENT) < s + 1)
          __builtin_amdgcn_s_sleep(1);
      }
      __syncthreads();
      const unsigned short* src = (s & 1) ? hgl1 : hgl0;
      {
        int c = tid;  // chunks of 8 bf16
        uint4 v = reinterpret_cast<const uint4*>(src)[c];
        int b = c / 48, j8 = c - b * 48;
        *reinterpret_cast<uint4*>((char*)hls + ((b * 768 + j8 * 16) ^ (b << 4))) = v;
        if (tid < 128){
          c = tid + 256;
          v = reinterpret_cast<const uint4*>(src)[c];
          b = c / 48; j8 = c - b * 48;
          *reinterpret_cast<uint4*>((char*)hls + ((b * 768 + j8 * 16) ^ (b << 4))) = v;
        }
      }
      __syncthreads();
    }
  }
}

// ---------------- gather + concat + relu (per batch) ----------------
__global__ void k_gather(const unsigned short* __restrict__ srep,
                         const unsigned short* __restrict__ erep,
                         const int* __restrict__ sidx, int b,
                         uint4* __restrict__ cat)
{
  int i = blockIdx.x * blockDim.x + threadIdx.x;  // s*192 + c
  if (i >= S_ * 192) return;
  int s = i / 192, c = i % 192;
  int i0 = sidx[(size_t)(b * S_ + s) * 2 + 0];
  int i1 = sidx[(size_t)(b * S_ + s) * 2 + 1];
  i0 = min(max(i0, 0), L_ - 1);
  i1 = min(max(i1, 0), L_ - 1);
  uint4 v;
  if (c < 96)
    v = reinterpret_cast<const uint4*>(srep + (size_t)(b * L_ + i0) * H_)[c];
  else
    v = reinterpret_cast<const uint4*>(erep + (size_t)(b * L_ + i1) * H_)[c - 96];
  v.x = relu2(v.x); v.y = relu2(v.y); v.z = relu2(v.z); v.w = relu2(v.w);
  cat[i] = v;
}

extern "C" void kernel_launch(void* const* d_in, const int* in_sizes, int n_in,
                              void* d_out, int out_size, void* d_ws, size_t ws_size,
                              hipStream_t stream)
{
  (void)in_sizes; (void)n_in; (void)out_size; (void)ws_size;
  const float* we     = (const float*)d_in[0];
  const int*   mask   = (const int*)  d_in[1];
  const int*   sidx   = (const int*)  d_in[2];
  const float* pe     = (const float*)d_in[3];
  const float* w_ih_f = (const float*)d_in[4];
  const float* w_hh_f = (const float*)d_in[5];
  const float* b_ih_f = (const float*)d_in[6];
  const float* b_hh_f = (const float*)d_in[7];
  const float* w_ih_b = (const float*)d_in[8];
  const float* w_hh_b = (const float*)d_in[9];
  const float* b_ih_b = (const float*)d_in[10];
  const float* b_hh_b = (const float*)d_in[11];
  const float* sw1 = (const float*)d_in[12]; const float* sb1 = (const float*)d_in[13];
  const float* sw2 = (const float*)d_in[14]; const float* sb2 = (const float*)d_in[15];
  const float* ew1 = (const float*)d_in[16]; const float* eb1 = (const float*)d_in[17];
  const float* ew2 = (const float*)d_in[18]; const float* eb2 = (const float*)d_in[19];
  const float* ow1 = (const float*)d_in[20]; const float* ob1 = (const float*)d_in[21];
  const float* ow2 = (const float*)d_in[22]; const float* ob2 = (const float*)d_in[23];
  const float* pw1 = (const float*)d_in[24]; const float* pb1 = (const float*)d_in[25];
  const float* pw2 = (const float*)d_in[26]; const float* pb2 = (const float*)d_in[27];

  char* wsp = (char*)d_ws; size_t off = 0;
  auto alloc = [&](size_t bytes) -> void* {
    void* p = wsp + off;
    off += (bytes + 255) & ~(size_t)255;
    return p;
  };

  unsigned short* we_bf   = (unsigned short*)alloc((size_t)4096*768*2);
  unsigned short* wihf_bf = (unsigned short*)alloc((size_t)1536*768*2);
  unsigned short* wihb_bf = (unsigned short*)alloc((size_t)1536*768*2);
  float* bc_f = (float*)alloc((size_t)1536*4);
  float* bc_b = (float*)alloc((size_t)1536*4);
  float* xg_f = (float*)alloc((size_t)4096*1536*4);
  float* xg_b = (float*)alloc((size_t)4096*1536*4);
  unsigned short* whh_bf = (unsigned short*)alloc((size_t)2*1536*384*2);
  unsigned short* hglob  = (unsigned short*)alloc((size_t)2*2*8*384*2);
  int* flags = (int*)alloc(64*sizeof(int));
  unsigned short* h_bf  = (unsigned short*)alloc((size_t)4096*768*2);
  unsigned short* sw1b  = (unsigned short*)alloc((size_t)3072*768*2);
  unsigned short* sw2b  = (unsigned short*)alloc((size_t)768*3072*2);
  unsigned short* ew1b  = (unsigned short*)alloc((size_t)3072*768*2);
  unsigned short* ew2b  = (unsigned short*)alloc((size_t)768*3072*2);
  unsigned short* ow1b  = (unsigned short*)alloc((size_t)3072*1536*2);
  unsigned short* ow2b  = (unsigned short*)alloc((size_t)768*3072*2);
  unsigned short* pw1b  = (unsigned short*)alloc((size_t)3072*768*2);
  unsigned short* pw2b  = (unsigned short*)alloc((size_t)768*3072*2);
  unsigned short* srep  = (unsigned short*)alloc((size_t)4096*768*2);
  unsigned short* erep  = (unsigned short*)alloc((size_t)4096*768*2);
  unsigned short* midb  = (unsigned short*)alloc((size_t)6144*3072*2);
  unsigned short* catb  = (unsigned short*)alloc((size_t)6144*1536*2);
  unsigned short* pe_bf = (unsigned short*)alloc((size_t)200*768*2);
  unsigned short* pmid  = (unsigned short*)alloc((size_t)200*3072*2);

  auto cast = [&](const float* s, unsigned short* d, size_t n){
    long n4 = (long)(n / 4);
    int grid = (int)((n4 + 255) / 256);
    k_cast_bf16<<<grid, 256, 0, stream>>>(s, d, n4);
  };

  hipMemsetAsync(flags, 0, 64*sizeof(int), stream);

  cast(we, we_bf, (size_t)4096*768);
  cast(w_ih_f, wihf_bf, (size_t)1536*768);
  cast(w_ih_b, wihb_bf, (size_t)1536*768);
  cast(w_hh_f, whh_bf,               (size_t)1536*384);
  cast(w_hh_b, whh_bf + 1536*384,    (size_t)1536*384);
  cast(sw1, sw1b, (size_t)3072*768);  cast(sw2, sw2b, (size_t)768*3072);
  cast(ew1, ew1b, (size_t)3072*768);  cast(ew2, ew2b, (size_t)768*3072);
  cast(ow1, ow1b, (size_t)3072*1536); cast(ow2, ow2b, (size_t)768*3072);
  cast(pw1, pw1b, (size_t)3072*768);  cast(pw2, pw2b, (size_t)768*3072);
  cast(pe, pe_bf, (size_t)200*768);

  k_biascomb<<<6, 256, 0, stream>>>(b_ih_f, b_hh_f, bc_f, 1536);
  k_biascomb<<<6, 256, 0, stream>>>(b_ih_b, b_hh_b, bc_b, 1536);

  dim3 blk(256);
  // input-gate precompute (both biases folded in)
  k_gemm_nt<0,0><<<dim3(1536/128, 4096/128), blk, 0, stream>>>(we_bf, wihf_bf, bc_f, xg_f, 4096, 1536, 768);
  k_gemm_nt<0,0><<<dim3(1536/128, 4096/128), blk, 0, stream>>>(we_bf, wihb_bf, bc_b, xg_b, 4096, 1536, 768);

  k_lstm2<<<64, 256, 0, stream>>>(xg_f, xg_b, whh_bf, mask, h_bf, hglob, flags);

  // start / end MLPs (bf16 chain)
  k_gemm_nt<1,1><<<dim3(3072/128, 4096/128), blk, 0, stream>>>(h_bf, sw1b, sb1, midb, 4096, 3072, 768);
  k_gemm_nt<0,1><<<dim3( 768/128, 4096/128), blk, 0, stream>>>(midb, sw2b, sb2, srep, 4096,  768, 3072);
  k_gemm_nt<1,1><<<dim3(3072/128, 4096/128), blk, 0, stream>>>(h_bf, ew1b, eb1, midb, 4096, 3072, 768);
  k_gemm_nt<0,1><<<dim3( 768/128, 4096/128), blk, 0, stream>>>(midb, ew2b, eb2, erep, 4096,  768, 3072);

  float* outp = (float*)d_out;
  for (int b = 0; b < 8; b++){
    k_gather<<<(S_*192)/256, 256, 0, stream>>>(srep, erep, sidx, b, (uint4*)catb);
    k_gemm_nt<1,1><<<dim3(3072/128, 6144/128), blk, 0, stream>>>(catb, ow1b, ob1, midb, 6144, 3072, 1536);
    k_gemm_nt<0,0><<<dim3( 768/128, 6144/128), blk, 0, stream>>>(midb, ow2b, ob2,
                                                                 outp + (size_t)b * S_ * H_, 6144, 768, 3072);
  }

  // prompt projection
  k_gemm_nt<1,1><<<dim3(3072/128, 2), blk, 0, stream>>>(pe_bf, pw1b, pb1, pmid, 200, 3072, 768);
  k_gemm_nt<0,0><<<dim3( 768/128, 2), blk, 0, stream>>>(pmid, pw2b, pb2,
                                                        outp + (size_t)37748736, 200, 768, 3072);
}

// Round 3
// 5026.340 us; speedup vs baseline: 1.7711x; 1.4836x over previous
//
#include <hip/hip_runtime.h>
#include <hip/hip_bf16.h>
#include <stdint.h>

#define B_ 8
#define L_ 512
#define H_ 768
#define WW_ 12
#define C_ 25
#define S_ (L_*WW_)   // 6144
#define HH 384        // H/2
#define G4 1536       // 4*HH

using bf16x8 = __attribute__((ext_vector_type(8))) short;
using f32x4  = __attribute__((ext_vector_type(4))) float;

static __device__ __forceinline__ unsigned short f2bf(float x){
  unsigned u = __float_as_uint(x);
  unsigned r = (u + 0x7FFFu + ((u >> 16) & 1u)) >> 16;
  return (unsigned short)r;
}

static __device__ __forceinline__ float sigmoid_f(float x){
  x = fminf(15.f, fmaxf(-15.f, x));
  return 1.f / (1.f + __expf(-x));
}
static __device__ __forceinline__ float tanh_f(float x){
  x = fminf(15.f, fmaxf(-15.f, x));
  float e = __expf(-2.f * x);
  return (1.f - e) / (1.f + e);
}
static __device__ __forceinline__ unsigned relu2(unsigned u){
  if (u & 0x80000000u) u &= 0x0000FFFFu;
  if (u & 0x00008000u) u &= 0xFFFF0000u;
  return u;
}

// ---------------- fp32 -> bf16 cast (n multiple of 4) ----------------
__global__ void k_cast_bf16(const float* __restrict__ s, unsigned short* __restrict__ d, long n4){
  long i = (long)blockIdx.x * blockDim.x + threadIdx.x;
  if (i >= n4) return;
  float4 v = reinterpret_cast<const float4*>(s)[i];
  ushort4 o;
  o.x = f2bf(v.x); o.y = f2bf(v.y); o.z = f2bf(v.z); o.w = f2bf(v.w);
  reinterpret_cast<ushort4*>(d)[i] = o;
}

__global__ void k_biascomb(const float* __restrict__ a, const float* __restrict__ b,
                           float* __restrict__ o, int n){
  int i = blockIdx.x * blockDim.x + threadIdx.x;
  if (i < n) o[i] = a[i] + b[i];
}

// ---------------- generic NT GEMM: C[M,N] = act(A[M,K] @ B[N,K]^T + bias) ----
template<int ACT, int OUTBF>
__global__ __launch_bounds__(256) void k_gemm_nt(
    const unsigned short* __restrict__ A, const unsigned short* __restrict__ Bm,
    const float* __restrict__ bias, void* __restrict__ Cout,
    int M, int N, int K)
{
  const int lane = threadIdx.x & 63;
  const int wave = threadIdx.x >> 6;
  const int wr = wave >> 1, wc = wave & 1;
  const int l16 = lane & 15, lq = lane >> 4;
  const int m0 = blockIdx.y * 128 + wr * 64;
  const int n0 = blockIdx.x * 128 + wc * 64;

  f32x4 acc[4][4];
  #pragma unroll
  for (int a = 0; a < 4; a++)
    #pragma unroll
    for (int b = 0; b < 4; b++)
      acc[a][b] = (f32x4)0.f;

  const unsigned short* Ap[4]; bool am[4];
  #pragma unroll
  for (int mi = 0; mi < 4; mi++){
    int row = m0 + mi * 16 + l16;
    am[mi] = row < M;
    int rc = am[mi] ? row : 0;
    Ap[mi] = A + (size_t)rc * K + lq * 8;
  }
  const unsigned short* Bp[4];
  #pragma unroll
  for (int ni = 0; ni < 4; ni++){
    int col = n0 + ni * 16 + l16;
    Bp[ni] = Bm + (size_t)col * K + lq * 8;
  }

  for (int k = 0; k < K; k += 32){
    bf16x8 af[4], bfr[4];
    #pragma unroll
    for (int mi = 0; mi < 4; mi++){
      bf16x8 v = {0,0,0,0,0,0,0,0};
      if (am[mi]) v = *reinterpret_cast<const bf16x8*>(Ap[mi] + k);
      af[mi] = v;
    }
    #pragma unroll
    for (int ni = 0; ni < 4; ni++)
      bfr[ni] = *reinterpret_cast<const bf16x8*>(Bp[ni] + k);
    #pragma unroll
    for (int mi = 0; mi < 4; mi++)
      #pragma unroll
      for (int ni = 0; ni < 4; ni++)
        acc[mi][ni] = __builtin_amdgcn_mfma_f32_16x16x32_bf16(af[mi], bfr[ni], acc[mi][ni], 0, 0, 0);
  }

  #pragma unroll
  for (int mi = 0; mi < 4; mi++){
    #pragma unroll
    for (int r = 0; r < 4; r++){
      int row = m0 + mi * 16 + lq * 4 + r;
      if (row >= M) continue;
      #pragma unroll
      for (int ni = 0; ni < 4; ni++){
        int col = n0 + ni * 16 + l16;
        float v = acc[mi][ni][r] + bias[col];
        if (ACT) v = v > 0.f ? v : 0.f;
        if (OUTBF) ((unsigned short*)Cout)[(size_t)row * N + col] = f2bf(v);
        else       ((float*)Cout)[(size_t)row * N + col] = v;
      }
    }
  }
}

// ---------------- distributed LSTM, fence-free tagged-word exchange -------
// Grid 12 = dir(2) x part(6). Part owns 64 hidden units (256 gate rows).
// Block 512 thr = 8 waves; W_hh slice resident as 24 MFMA B-frags/wave.
// Cross-block h exchange: hg[dir][parity][b*384+u] = (tag<<16)|bf16(h),
// tag = s+1, relaxed AGENT-scope atomics (sc1). Readers poll data words.
static __device__ __forceinline__ unsigned long long ald8(const unsigned long long* p){
  return __hip_atomic_load(p, __ATOMIC_RELAXED, __HIP_MEMORY_SCOPE_AGENT);
}

__global__ __launch_bounds__(512, 2) void k_lstm3(
    const float* __restrict__ xgf, const float* __restrict__ xgb,
    const unsigned short* __restrict__ Wbf,   // [2][1536][384] bf16
    const int* __restrict__ mask,
    unsigned short* __restrict__ hbf,         // [4096][768] bf16 out (masked)
    unsigned int* __restrict__ hg)            // [2][2][3072] tagged words (pre-zeroed)
{
  const int dir  = blockIdx.x / 6;
  const int part = blockIdx.x % 6;
  const int tid  = threadIdx.x;
  const int lane = tid & 63;
  const int w    = tid >> 6;            // wave 0..7
  const int l16  = lane & 15, lq = lane >> 4;

  __shared__ alignas(16) unsigned short hls[8 * HH];   // 6 KB, XOR-swizzled
  __shared__ float gsl[256 * 9];                        // padded gate staging

  const float* xg = dir ? xgb : xgf;
  const unsigned short* Wg = Wbf + (size_t)dir * G4 * HH;
  unsigned int* hgd = hg + dir * 2 * (8 * HH);

  // resident W_hh B-frags: wave w covers local gate-rows w*32 .. w*32+31
  bf16x8 bfr0[12], bfr1[12];
  {
    int r0 = w * 32 + l16;          // ntile 0
    int r1 = w * 32 + 16 + l16;     // ntile 1
    int g0 = r0 >> 6, j0u = r0 & 63;
    int g1 = r1 >> 6, j1u = r1 & 63;
    const unsigned short* p0 = Wg + ((size_t)g0 * HH + part * 64 + j0u) * HH + lq * 8;
    const unsigned short* p1 = Wg + ((size_t)g1 * HH + part * 64 + j1u) * HH + lq * 8;
    #pragma unroll
    for (int kf = 0; kf < 12; kf++){
      bfr0[kf] = *reinterpret_cast<const bf16x8*>(p0 + kf * 32);
      bfr1[kf] = *reinterpret_cast<const bf16x8*>(p1 + kf * 32);
    }
  }

  if (tid < 384) reinterpret_cast<uint4*>(hls)[tid] = uint4{0,0,0,0};

  const int cb = tid >> 6;          // combine: batch = wave
  const int cj = tid & 63;          // combine: unit within part
  const int cu = part * 64 + cj;    // global unit
  float c_state = 0.f;

  // reader word range: 6 consecutive words (same batch row; 384 % 6 == 0)
  const int w0  = tid * 6;
  const int rb  = w0 / HH;
  const int ru  = w0 % HH;

  __syncthreads();

  for (int s = 0; s < L_; s++){
    const int t = dir ? (L_ - 1 - s) : s;

    // prefetch xg + mask (consumed in combine; hides HBM latency)
    const float* xr = xg + ((size_t)cb * L_ + t) * G4;
    float xi  = xr[cu];
    float xf  = xr[HH + cu];
    float xgg = xr[2 * HH + cu];
    float xo  = xr[3 * HH + cu];
    int   mv  = mask[cb * L_ + t];

    if (s > 0){
      const unsigned long long tg = (unsigned long long)s;  // expected tag
      const unsigned long long* P =
        reinterpret_cast<const unsigned long long*>(hgd + ((s - 1) & 1) * (8 * HH) + w0);
      unsigned long long v0 = ald8(P), v1 = ald8(P + 1), v2 = ald8(P + 2);
      while ((((v0 >> 16) & 0xFFFFull) != tg) || ((v0 >> 48) != tg)) v0 = ald8(P);
      while ((((v1 >> 16) & 0xFFFFull) != tg) || ((v1 >> 48) != tg)) v1 = ald8(P + 1);
      while ((((v2 >> 16) & 0xFFFFull) != tg) || ((v2 >> 48) != tg)) v2 = ald8(P + 2);
      unsigned p01 = (unsigned)(v0 & 0xFFFFu) | ((unsigned)((v0 >> 32) & 0xFFFFu) << 16);
      unsigned p23 = (unsigned)(v1 & 0xFFFFu) | ((unsigned)((v1 >> 32) & 0xFFFFu) << 16);
      unsigned p45 = (unsigned)(v2 & 0xFFFFu) | ((unsigned)((v2 >> 32) & 0xFFFFu) << 16);
      *reinterpret_cast<unsigned*>((char*)hls + ((rb * 768 + (ru    ) * 2) ^ (rb << 4))) = p01;
      *reinterpret_cast<unsigned*>((char*)hls + ((rb * 768 + (ru + 2) * 2) ^ (rb << 4))) = p23;
      *reinterpret_cast<unsigned*>((char*)hls + ((rb * 768 + (ru + 4) * 2) ^ (rb << 4))) = p45;
    }
    __syncthreads();

    // gates = h @ Wslice^T : per wave 2 n-tiles x 12 k-frags
    f32x4 acc0 = (f32x4)0.f, acc1 = (f32x4)0.f;
    const int arow = l16 & 7;
    #pragma unroll
    for (int kf = 0; kf < 12; kf++){
      int by = (arow * 768 + kf * 64 + lq * 16) ^ (arow << 4);
      bf16x8 a = *reinterpret_cast<const bf16x8*>((const char*)hls + by);
      acc0 = __builtin_amdgcn_mfma_f32_16x16x32_bf16(a, bfr0[kf], acc0, 0, 0, 0);
      acc1 = __builtin_amdgcn_mfma_f32_16x16x32_bf16(a, bfr1[kf], acc1, 0, 0, 0);
    }
    if (lq < 2){
      int n0r = w * 32 + l16;
      int n1r = w * 32 + 16 + l16;
      #pragma unroll
      for (int r = 0; r < 4; r++){
        gsl[n0r * 9 + lq * 4 + r] = acc0[r];
        gsl[n1r * 9 + lq * 4 + r] = acc1[r];
      }
    }
    __syncthreads();

    // combine: thread = (batch cb, unit cj)
    {
      float gi = gsl[(0 * 64 + cj) * 9 + cb] + xi;
      float gf = gsl[(1 * 64 + cj) * 9 + cb] + xf;
      float gg = gsl[(2 * 64 + cj) * 9 + cb] + xgg;
      float go = gsl[(3 * 64 + cj) * 9 + cb] + xo;
      c_state = sigmoid_f(gf) * c_state + sigmoid_f(gi) * tanh_f(gg);
      float h = sigmoid_f(go) * tanh_f(c_state);
      unsigned short hb = f2bf(h);
      // own slice into LDS for next step
      *reinterpret_cast<unsigned short*>((char*)hls + ((cb * 768 + cu * 2) ^ (cb << 4))) = hb;
      // tagged word to L3 (relaxed agent atomic = sc1, no fence)
      unsigned word = ((unsigned)(s + 1) << 16) | (unsigned)hb;
      __hip_atomic_store(&hgd[(s & 1) * (8 * HH) + cb * HH + cu], word,
                         __ATOMIC_RELAXED, __HIP_MEMORY_SCOPE_AGENT);
      // masked output (fire-and-forget)
      hbf[((size_t)cb * L_ + t) * H_ + dir * HH + cu] = f2bf(h * (float)mv);
    }
    // no barrier needed here: next-iter poll/ds_writes touch disjoint LDS slots
  }
}

// ---------------- gather + concat + relu (per batch) ----------------
__global__ void k_gather(const unsigned short* __restrict__ srep,
                         const unsigned short* __restrict__ erep,
                         const int* __restrict__ sidx, int b,
                         uint4* __restrict__ cat)
{
  int i = blockIdx.x * blockDim.x + threadIdx.x;  // s*192 + c
  if (i >= S_ * 192) return;
  int s = i / 192, c = i % 192;
  int i0 = sidx[(size_t)(b * S_ + s) * 2 + 0];
  int i1 = sidx[(size_t)(b * S_ + s) * 2 + 1];
  i0 = min(max(i0, 0), L_ - 1);
  i1 = min(max(i1, 0), L_ - 1);
  uint4 v;
  if (c < 96)
    v = reinterpret_cast<const uint4*>(srep + (size_t)(b * L_ + i0) * H_)[c];
  else
    v = reinterpret_cast<const uint4*>(erep + (size_t)(b * L_ + i1) * H_)[c - 96];
  v.x = relu2(v.x); v.y = relu2(v.y); v.z = relu2(v.z); v.w = relu2(v.w);
  cat[i] = v;
}

extern "C" void kernel_launch(void* const* d_in, const int* in_sizes, int n_in,
                              void* d_out, int out_size, void* d_ws, size_t ws_size,
                              hipStream_t stream)
{
  (void)in_sizes; (void)n_in; (void)out_size; (void)ws_size;
  const float* we     = (const float*)d_in[0];
  const int*   mask   = (const int*)  d_in[1];
  const int*   sidx   = (const int*)  d_in[2];
  const float* pe     = (const float*)d_in[3];
  const float* w_ih_f = (const float*)d_in[4];
  const float* w_hh_f = (const float*)d_in[5];
  const float* b_ih_f = (const float*)d_in[6];
  const float* b_hh_f = (const float*)d_in[7];
  const float* w_ih_b = (const float*)d_in[8];
  const float* w_hh_b = (const float*)d_in[9];
  const float* b_ih_b = (const float*)d_in[10];
  const float* b_hh_b = (const float*)d_in[11];
  const float* sw1 = (const float*)d_in[12]; const float* sb1 = (const float*)d_in[13];
  const float* sw2 = (const float*)d_in[14]; const float* sb2 = (const float*)d_in[15];
  const float* ew1 = (const float*)d_in[16]; const float* eb1 = (const float*)d_in[17];
  const float* ew2 = (const float*)d_in[18]; const float* eb2 = (const float*)d_in[19];
  const float* ow1 = (const float*)d_in[20]; const float* ob1 = (const float*)d_in[21];
  const float* ow2 = (const float*)d_in[22]; const float* ob2 = (const float*)d_in[23];
  const float* pw1 = (const float*)d_in[24]; const float* pb1 = (const float*)d_in[25];
  const float* pw2 = (const float*)d_in[26]; const float* pb2 = (const float*)d_in[27];

  char* wsp = (char*)d_ws; size_t off = 0;
  auto alloc = [&](size_t bytes) -> void* {
    void* p = wsp + off;
    off += (bytes + 255) & ~(size_t)255;
    return p;
  };

  unsigned short* we_bf   = (unsigned short*)alloc((size_t)4096*768*2);
  unsigned short* wihf_bf = (unsigned short*)alloc((size_t)1536*768*2);
  unsigned short* wihb_bf = (unsigned short*)alloc((size_t)1536*768*2);
  float* bc_f = (float*)alloc((size_t)1536*4);
  float* bc_b = (float*)alloc((size_t)1536*4);
  float* xg_f = (float*)alloc((size_t)4096*1536*4);
  float* xg_b = (float*)alloc((size_t)4096*1536*4);
  unsigned short* whh_bf = (unsigned short*)alloc((size_t)2*1536*384*2);
  unsigned int* hg = (unsigned int*)alloc((size_t)2*2*8*384*4);
  unsigned short* h_bf  = (unsigned short*)alloc((size_t)4096*768*2);
  unsigned short* sw1b  = (unsigned short*)alloc((size_t)3072*768*2);
  unsigned short* sw2b  = (unsigned short*)alloc((size_t)768*3072*2);
  unsigned short* ew1b  = (unsigned short*)alloc((size_t)3072*768*2);
  unsigned short* ew2b  = (unsigned short*)alloc((size_t)768*3072*2);
  unsigned short* ow1b  = (unsigned short*)alloc((size_t)3072*1536*2);
  unsigned short* ow2b  = (unsigned short*)alloc((size_t)768*3072*2);
  unsigned short* pw1b  = (unsigned short*)alloc((size_t)3072*768*2);
  unsigned short* pw2b  = (unsigned short*)alloc((size_t)768*3072*2);
  unsigned short* srep  = (unsigned short*)alloc((size_t)4096*768*2);
  unsigned short* erep  = (unsigned short*)alloc((size_t)4096*768*2);
  unsigned short* midb  = (unsigned short*)alloc((size_t)6144*3072*2);
  unsigned short* catb  = (unsigned short*)alloc((size_t)6144*1536*2);
  unsigned short* pe_bf = (unsigned short*)alloc((size_t)200*768*2);
  unsigned short* pmid  = (unsigned short*)alloc((size_t)200*3072*2);

  auto cast = [&](const float* s, unsigned short* d, size_t n){
    long n4 = (long)(n / 4);
    int grid = (int)((n4 + 255) / 256);
    k_cast_bf16<<<grid, 256, 0, stream>>>(s, d, n4);
  };

  hipMemsetAsync(hg, 0, (size_t)2*2*8*384*4, stream);

  cast(we, we_bf, (size_t)4096*768);
  cast(w_ih_f, wihf_bf, (size_t)1536*768);
  cast(w_ih_b, wihb_bf, (size_t)1536*768);
  cast(w_hh_f, whh_bf,               (size_t)1536*384);
  cast(w_hh_b, whh_bf + 1536*384,    (size_t)1536*384);
  cast(sw1, sw1b, (size_t)3072*768);  cast(sw2, sw2b, (size_t)768*3072);
  cast(ew1, ew1b, (size_t)3072*768);  cast(ew2, ew2b, (size_t)768*3072);
  cast(ow1, ow1b, (size_t)3072*1536); cast(ow2, ow2b, (size_t)768*3072);
  cast(pw1, pw1b, (size_t)3072*768);  cast(pw2, pw2b, (size_t)768*3072);
  cast(pe, pe_bf, (size_t)200*768);

  k_biascomb<<<6, 256, 0, stream>>>(b_ih_f, b_hh_f, bc_f, 1536);
  k_biascomb<<<6, 256, 0, stream>>>(b_ih_b, b_hh_b, bc_b, 1536);

  dim3 blk(256);
  // input-gate precompute (both biases folded in)
  k_gemm_nt<0,0><<<dim3(1536/128, 4096/128), blk, 0, stream>>>(we_bf, wihf_bf, bc_f, xg_f, 4096, 1536, 768);
  k_gemm_nt<0,0><<<dim3(1536/128, 4096/128), blk, 0, stream>>>(we_bf, wihb_bf, bc_b, xg_b, 4096, 1536, 768);

  k_lstm3<<<12, 512, 0, stream>>>(xg_f, xg_b, whh_bf, mask, h_bf, hg);

  // start / end MLPs (bf16 chain)
  k_gemm_nt<1,1><<<dim3(3072/128, 4096/128), blk, 0, stream>>>(h_bf, sw1b, sb1, midb, 4096, 3072, 768);
  k_gemm_nt<0,1><<<dim3( 768/128, 4096/128), blk, 0, stream>>>(midb, sw2b, sb2, srep, 4096,  768, 3072);
  k_gemm_nt<1,1><<<dim3(3072/128, 4096/128), blk, 0, stream>>>(h_bf, ew1b, eb1, midb, 4096, 3072, 768);
  k_gemm_nt<0,1><<<dim3( 768/128, 4096/128), blk, 0, stream>>>(midb, ew2b, eb2, erep, 4096,  768, 3072);

  float* outp = (float*)d_out;
  for (int b = 0; b < 8; b++){
    k_gather<<<(S_*192)/256, 256, 0, stream>>>(srep, erep, sidx, b, (uint4*)catb);
    k_gemm_nt<1,1><<<dim3(3072/128, 6144/128), blk, 0, stream>>>(catb, ow1b, ob1, midb, 6144, 3072, 1536);
    k_gemm_nt<0,0><<<dim3( 768/128, 6144/128), blk, 0, stream>>>(midb, ow2b, ob2,
                                                                 outp + (size_t)b * S_ * H_, 6144, 768, 3072);
  }

  // prompt projection
  k_gemm_nt<1,1><<<dim3(3072/128, 2), blk, 0, stream>>>(pe_bf, pw1b, pb1, pmid, 200, 3072, 768);
  k_gemm_nt<0,0><<<dim3( 768/128, 2), blk, 0, stream>>>(pmid, pw2b, pb2,
                                                        outp + (size_t)37748736, 200, 768, 3072);
}

// Round 4
// 2116.383 us; speedup vs baseline: 4.2063x; 2.3750x over previous
//
#include <hip/hip_runtime.h>
#include <hip/hip_bf16.h>
#include <stdint.h>

#define B_ 8
#define L_ 512
#define H_ 768
#define WW_ 12
#define C_ 25
#define S_ (L_*WW_)   // 6144
#define HH 384        // H/2
#define G4 1536       // 4*HH

using bf16x8 = __attribute__((ext_vector_type(8))) short;
using f32x4  = __attribute__((ext_vector_type(4))) float;

static __device__ __forceinline__ unsigned short f2bf(float x){
  unsigned u = __float_as_uint(x);
  unsigned r = (u + 0x7FFFu + ((u >> 16) & 1u)) >> 16;
  return (unsigned short)r;
}
static __device__ __forceinline__ float bflo(unsigned u){ return __uint_as_float(u << 16); }
static __device__ __forceinline__ float bfhi(unsigned u){ return __uint_as_float(u & 0xFFFF0000u); }

static __device__ __forceinline__ float sigmoid_f(float x){
  x = fminf(15.f, fmaxf(-15.f, x));
  return 1.f / (1.f + __expf(-x));
}
static __device__ __forceinline__ float tanh_f(float x){
  x = fminf(15.f, fmaxf(-15.f, x));
  float e = __expf(-2.f * x);
  return (1.f - e) / (1.f + e);
}

// global -> LDS direct DMA, 16 B per lane (dest must be wave-uniform base + lane*16)
static __device__ __forceinline__ void gl_lds16(const unsigned short* g, unsigned short* l){
  __builtin_amdgcn_global_load_lds(
      (const __attribute__((address_space(1))) unsigned int*)g,
      (__attribute__((address_space(3))) unsigned int*)l,
      16, 0, 0);
}

// ---------------- fp32 -> bf16 cast (n multiple of 4) ----------------
__global__ void k_cast_bf16(const float* __restrict__ s, unsigned short* __restrict__ d, long n4){
  long i = (long)blockIdx.x * blockDim.x + threadIdx.x;
  if (i >= n4) return;
  float4 v = reinterpret_cast<const float4*>(s)[i];
  ushort4 o;
  o.x = f2bf(v.x); o.y = f2bf(v.y); o.z = f2bf(v.z); o.w = f2bf(v.w);
  reinterpret_cast<ushort4*>(d)[i] = o;
}

__global__ void k_biascomb(const float* __restrict__ a, const float* __restrict__ b,
                           float* __restrict__ o, int n){
  int i = blockIdx.x * blockDim.x + threadIdx.x;
  if (i < n) o[i] = a[i] + b[i];
}

// ---------------- LDS-staged NT GEMM (m97 structure) ----------------
// C[M,N] = act(A[M,K] @ B[N,K]^T + bias). A lda=K, B row stride ldb (>=K).
// 128x128 tile, BK=64, 4 waves (2x2). LDS A/B tiles [128][64] bf16,
// XOR-swizzled: 16B slot p holds global slot p^(row&7). Staged via
// global_load_lds (linear dest, pre-swizzled global source). N%128==0.
template<int ACT, int OUTBF>
__global__ __launch_bounds__(256) void k_gemm2(
    const unsigned short* __restrict__ A, const unsigned short* __restrict__ Bm,
    const float* __restrict__ bias, void* __restrict__ Cout,
    int M, int N, int K, int ldb)
{
  __shared__ unsigned short Al[128 * 64];
  __shared__ unsigned short Bl[128 * 64];

  const int tid  = threadIdx.x;
  const int lane = tid & 63;
  const int wave = tid >> 6;
  const int wr = wave >> 1, wc = wave & 1;
  const int l16 = lane & 15, lq = lane >> 4;
  const int m0 = blockIdx.y * 128;
  const int n0 = blockIdx.x * 128;

  // staging source: thread -> (row r_, slot p_), global col = (p_^ (r_&7))*8
  const int r_ = tid >> 3;            // 0..31
  const int p_ = tid & 7;
  const int cS = ((p_ ^ (r_ & 7)) * 8);
  const unsigned short* Asrc[4];
  const unsigned short* Bsrc[4];
  #pragma unroll
  for (int i = 0; i < 4; i++){
    int ra = m0 + i * 32 + r_; ra = ra < M ? ra : (M - 1);
    Asrc[i] = A + (size_t)ra * K + cS;
    int rb = n0 + i * 32 + r_; rb = rb < N ? rb : (N - 1);
    Bsrc[i] = Bm + (size_t)rb * ldb + cS;
  }

  f32x4 acc[4][4];
  #pragma unroll
  for (int a = 0; a < 4; a++)
    #pragma unroll
    for (int b = 0; b < 4; b++)
      acc[a][b] = (f32x4)0.f;

  // read-phase swizzled slot offsets (lane-constant): slot = (kk*4+lq) ^ (l16&7)
  const int sw0 = ((0 * 4 + lq) ^ (l16 & 7)) * 16;
  const int sw1 = ((1 * 4 + lq) ^ (l16 & 7)) * 16;
  const int aBase = (wr * 64 + l16) * 128;   // byte row base (A)
  const int bBase = (wc * 64 + l16) * 128;   // byte row base (B)

  for (int k0 = 0; k0 < K; k0 += 64){
    #pragma unroll
    for (int i = 0; i < 4; i++)
      gl_lds16(Asrc[i] + k0, Al + i * 2048 + tid * 8);
    #pragma unroll
    for (int i = 0; i < 4; i++)
      gl_lds16(Bsrc[i] + k0, Bl + i * 2048 + tid * 8);
    __syncthreads();

    #pragma unroll
    for (int kk = 0; kk < 2; kk++){
      const int sw = kk ? sw1 : sw0;
      bf16x8 av[4], bv[4];
      #pragma unroll
      for (int mi = 0; mi < 4; mi++)
        av[mi] = *reinterpret_cast<const bf16x8*>((const char*)Al + aBase + mi * 2048 + sw);
      #pragma unroll
      for (int ni = 0; ni < 4; ni++)
        bv[ni] = *reinterpret_cast<const bf16x8*>((const char*)Bl + bBase + ni * 2048 + sw);
      #pragma unroll
      for (int mi = 0; mi < 4; mi++)
        #pragma unroll
        for (int ni = 0; ni < 4; ni++)
          acc[mi][ni] = __builtin_amdgcn_mfma_f32_16x16x32_bf16(av[mi], bv[ni], acc[mi][ni], 0, 0, 0);
    }
    __syncthreads();
  }

  #pragma unroll
  for (int mi = 0; mi < 4; mi++){
    #pragma unroll
    for (int r = 0; r < 4; r++){
      int row = m0 + wr * 64 + mi * 16 + lq * 4 + r;
      if (row >= M) continue;
      #pragma unroll
      for (int ni = 0; ni < 4; ni++){
        int col = n0 + wc * 64 + ni * 16 + l16;
        float v = acc[mi][ni][r] + bias[col];
        if (ACT) v = v > 0.f ? v : 0.f;
        if (OUTBF) ((unsigned short*)Cout)[(size_t)row * N + col] = f2bf(v);
        else       ((float*)Cout)[(size_t)row * N + col] = v;
      }
    }
  }
}

// ---------------- distributed LSTM, fence-free tagged-word exchange -------
static __device__ __forceinline__ unsigned long long ald8(const unsigned long long* p){
  return __hip_atomic_load(p, __ATOMIC_RELAXED, __HIP_MEMORY_SCOPE_AGENT);
}

__global__ __launch_bounds__(512, 2) void k_lstm3(
    const float* __restrict__ xgf, const float* __restrict__ xgb,
    const unsigned short* __restrict__ Wbf,   // [2][1536][384] bf16
    const int* __restrict__ mask,
    unsigned short* __restrict__ hbf,         // [4096][768] bf16 out (masked)
    unsigned int* __restrict__ hg)            // [2][2][3072] tagged words (pre-zeroed)
{
  const int dir  = blockIdx.x / 6;
  const int part = blockIdx.x % 6;
  const int tid  = threadIdx.x;
  const int lane = tid & 63;
  const int w    = tid >> 6;            // wave 0..7
  const int l16  = lane & 15, lq = lane >> 4;

  __shared__ alignas(16) unsigned short hls[8 * HH];   // 6 KB, XOR-swizzled
  __shared__ float gsl[256 * 9];                        // padded gate staging

  const float* xg = dir ? xgb : xgf;
  const unsigned short* Wg = Wbf + (size_t)dir * G4 * HH;
  unsigned int* hgd = hg + dir * 2 * (8 * HH);

  // resident W_hh B-frags: wave w covers local gate-rows w*32 .. w*32+31
  bf16x8 bfr0[12], bfr1[12];
  {
    int r0 = w * 32 + l16;
    int r1 = w * 32 + 16 + l16;
    int g0 = r0 >> 6, j0u = r0 & 63;
    int g1 = r1 >> 6, j1u = r1 & 63;
    const unsigned short* p0 = Wg + ((size_t)g0 * HH + part * 64 + j0u) * HH + lq * 8;
    const unsigned short* p1 = Wg + ((size_t)g1 * HH + part * 64 + j1u) * HH + lq * 8;
    #pragma unroll
    for (int kf = 0; kf < 12; kf++){
      bfr0[kf] = *reinterpret_cast<const bf16x8*>(p0 + kf * 32);
      bfr1[kf] = *reinterpret_cast<const bf16x8*>(p1 + kf * 32);
    }
  }

  if (tid < 384) reinterpret_cast<uint4*>(hls)[tid] = uint4{0,0,0,0};

  const int cb = tid >> 6;          // combine: batch = wave
  const int cj = tid & 63;          // combine: unit within part
  const int cu = part * 64 + cj;    // global unit
  float c_state = 0.f;

  const int w0  = tid * 6;
  const int rb  = w0 / HH;
  const int ru  = w0 % HH;

  // prefetch xg/mask for step 0
  float xi, xf, xgg, xo, mvf;
  {
    const int t0 = dir ? (L_ - 1) : 0;
    const float* xr = xg + ((size_t)cb * L_ + t0) * G4;
    xi = xr[cu]; xf = xr[HH + cu]; xgg = xr[2 * HH + cu]; xo = xr[3 * HH + cu];
    mvf = (float)mask[cb * L_ + t0];
  }

  __syncthreads();

  for (int s = 0; s < L_; s++){
    const int t = dir ? (L_ - 1 - s) : s;

    // issue next step's xg loads (consumed next iteration -> full-step latency hiding)
    float nxi = 0.f, nxf = 0.f, nxg = 0.f, nxo = 0.f, nmv = 0.f;
    if (s + 1 < L_){
      const int tn = dir ? (L_ - 2 - s) : (s + 1);
      const float* xr = xg + ((size_t)cb * L_ + tn) * G4;
      nxi = xr[cu]; nxf = xr[HH + cu]; nxg = xr[2 * HH + cu]; nxo = xr[3 * HH + cu];
      nmv = (float)mask[cb * L_ + tn];
    }

    if (s > 0){
      const unsigned long long tg = (unsigned long long)s;
      const unsigned long long* P =
        reinterpret_cast<const unsigned long long*>(hgd + ((s - 1) & 1) * (8 * HH) + w0);
      unsigned long long v0 = ald8(P), v1 = ald8(P + 1), v2 = ald8(P + 2);
      while ((((v0 >> 16) & 0xFFFFull) != tg) || ((v0 >> 48) != tg)) v0 = ald8(P);
      while ((((v1 >> 16) & 0xFFFFull) != tg) || ((v1 >> 48) != tg)) v1 = ald8(P + 1);
      while ((((v2 >> 16) & 0xFFFFull) != tg) || ((v2 >> 48) != tg)) v2 = ald8(P + 2);
      unsigned p01 = (unsigned)(v0 & 0xFFFFu) | ((unsigned)((v0 >> 32) & 0xFFFFu) << 16);
      unsigned p23 = (unsigned)(v1 & 0xFFFFu) | ((unsigned)((v1 >> 32) & 0xFFFFu) << 16);
      unsigned p45 = (unsigned)(v2 & 0xFFFFu) | ((unsigned)((v2 >> 32) & 0xFFFFu) << 16);
      *reinterpret_cast<unsigned*>((char*)hls + ((rb * 768 + (ru    ) * 2) ^ (rb << 4))) = p01;
      *reinterpret_cast<unsigned*>((char*)hls + ((rb * 768 + (ru + 2) * 2) ^ (rb << 4))) = p23;
      *reinterpret_cast<unsigned*>((char*)hls + ((rb * 768 + (ru + 4) * 2) ^ (rb << 4))) = p45;
    }
    __syncthreads();

    f32x4 acc0 = (f32x4)0.f, acc1 = (f32x4)0.f;
    const int arow = l16 & 7;
    #pragma unroll
    for (int kf = 0; kf < 12; kf++){
      int by = (arow * 768 + kf * 64 + lq * 16) ^ (arow << 4);
      bf16x8 a = *reinterpret_cast<const bf16x8*>((const char*)hls + by);
      acc0 = __builtin_amdgcn_mfma_f32_16x16x32_bf16(a, bfr0[kf], acc0, 0, 0, 0);
      acc1 = __builtin_amdgcn_mfma_f32_16x16x32_bf16(a, bfr1[kf], acc1, 0, 0, 0);
    }
    if (lq < 2){
      int n0r = w * 32 + l16;
      int n1r = w * 32 + 16 + l16;
      #pragma unroll
      for (int r = 0; r < 4; r++){
        gsl[n0r * 9 + lq * 4 + r] = acc0[r];
        gsl[n1r * 9 + lq * 4 + r] = acc1[r];
      }
    }
    __syncthreads();

    {
      float gi = gsl[(0 * 64 + cj) * 9 + cb] + xi;
      float gf = gsl[(1 * 64 + cj) * 9 + cb] + xf;
      float gg = gsl[(2 * 64 + cj) * 9 + cb] + xgg;
      float go = gsl[(3 * 64 + cj) * 9 + cb] + xo;
      c_state = sigmoid_f(gf) * c_state + sigmoid_f(gi) * tanh_f(gg);
      float h = sigmoid_f(go) * tanh_f(c_state);
      unsigned short hb = f2bf(h);
      *reinterpret_cast<unsigned short*>((char*)hls + ((cb * 768 + cu * 2) ^ (cb << 4))) = hb;
      unsigned word = ((unsigned)(s + 1) << 16) | (unsigned)hb;
      __hip_atomic_store(&hgd[(s & 1) * (8 * HH) + cb * HH + cu], word,
                         __ATOMIC_RELAXED, __HIP_MEMORY_SCOPE_AGENT);
      hbf[((size_t)cb * L_ + t) * H_ + dir * HH + cu] = f2bf(h * mvf);
    }

    xi = nxi; xf = nxf; xgg = nxg; xo = nxo; mvf = nmv;
  }
}

// ---------------- per-batch gather + add + bias + relu -> mid[6144][3072] ----
__global__ __launch_bounds__(384) void k_gadd(
    const unsigned short* __restrict__ Ps, const unsigned short* __restrict__ Pe,
    const int* __restrict__ sidx, const float* __restrict__ b1,
    int b, unsigned short* __restrict__ mid)
{
  const int s = blockIdx.x;        // span row 0..6143
  const int c = threadIdx.x;       // 16B chunk 0..383
  int i0 = sidx[((size_t)b * S_ + s) * 2 + 0];
  int i1 = sidx[((size_t)b * S_ + s) * 2 + 1];
  i0 = min(max(i0, 0), L_ - 1);
  i1 = min(max(i1, 0), L_ - 1);
  uint4 va = reinterpret_cast<const uint4*>(Ps + (size_t)(b * L_ + i0) * 3072)[c];
  uint4 ve = reinterpret_cast<const uint4*>(Pe + (size_t)(b * L_ + i1) * 3072)[c];
  float4 bb0 = reinterpret_cast<const float4*>(b1)[c * 2];
  float4 bb1 = reinterpret_cast<const float4*>(b1)[c * 2 + 1];
  const float* bp = (const float*)&bb0;
  float f[8];
  f[0] = bflo(va.x) + bflo(ve.x); f[1] = bfhi(va.x) + bfhi(ve.x);
  f[2] = bflo(va.y) + bflo(ve.y); f[3] = bfhi(va.y) + bfhi(ve.y);
  f[4] = bflo(va.z) + bflo(ve.z); f[5] = bfhi(va.z) + bfhi(ve.z);
  f[6] = bflo(va.w) + bflo(ve.w); f[7] = bfhi(va.w) + bfhi(ve.w);
  const float* bp1 = (const float*)&bb1;
  #pragma unroll
  for (int j = 0; j < 4; j++) f[j] += bp[j];
  #pragma unroll
  for (int j = 0; j < 4; j++) f[4 + j] += bp1[j];
  uint4 r;
  unsigned short e[8];
  #pragma unroll
  for (int j = 0; j < 8; j++){ float v = f[j] > 0.f ? f[j] : 0.f; e[j] = f2bf(v); }
  r.x = (unsigned)e[0] | ((unsigned)e[1] << 16);
  r.y = (unsigned)e[2] | ((unsigned)e[3] << 16);
  r.z = (unsigned)e[4] | ((unsigned)e[5] << 16);
  r.w = (unsigned)e[6] | ((unsigned)e[7] << 16);
  reinterpret_cast<uint4*>(mid)[(size_t)s * 384 + c] = r;
}

extern "C" void kernel_launch(void* const* d_in, const int* in_sizes, int n_in,
                              void* d_out, int out_size, void* d_ws, size_t ws_size,
                              hipStream_t stream)
{
  (void)in_sizes; (void)n_in; (void)out_size; (void)ws_size;
  const float* we     = (const float*)d_in[0];
  const int*   mask   = (const int*)  d_in[1];
  const int*   sidx   = (const int*)  d_in[2];
  const float* pe     = (const float*)d_in[3];
  const float* w_ih_f = (const float*)d_in[4];
  const float* w_hh_f = (const float*)d_in[5];
  const float* b_ih_f = (const float*)d_in[6];
  const float* b_hh_f = (const float*)d_in[7];
  const float* w_ih_b = (const float*)d_in[8];
  const float* w_hh_b = (const float*)d_in[9];
  const float* b_ih_b = (const float*)d_in[10];
  const float* b_hh_b = (const float*)d_in[11];
  const float* sw1 = (const float*)d_in[12]; const float* sb1 = (const float*)d_in[13];
  const float* sw2 = (const float*)d_in[14]; const float* sb2 = (const float*)d_in[15];
  const float* ew1 = (const float*)d_in[16]; const float* eb1 = (const float*)d_in[17];
  const float* ew2 = (const float*)d_in[18]; const float* eb2 = (const float*)d_in[19];
  const float* ow1 = (const float*)d_in[20]; const float* ob1 = (const float*)d_in[21];
  const float* ow2 = (const float*)d_in[22]; const float* ob2 = (const float*)d_in[23];
  const float* pw1 = (const float*)d_in[24]; const float* pb1 = (const float*)d_in[25];
  const float* pw2 = (const float*)d_in[26]; const float* pb2 = (const float*)d_in[27];

  char* wsp = (char*)d_ws; size_t off = 0;
  auto alloc = [&](size_t bytes) -> void* {
    void* p = wsp + off;
    off += (bytes + 255) & ~(size_t)255;
    return p;
  };

  unsigned short* we_bf   = (unsigned short*)alloc((size_t)4096*768*2);
  unsigned short* wihf_bf = (unsigned short*)alloc((size_t)1536*768*2);
  unsigned short* wihb_bf = (unsigned short*)alloc((size_t)1536*768*2);
  float* bc_f = (float*)alloc((size_t)1536*4);
  float* bc_b = (float*)alloc((size_t)1536*4);
  float* zerob = (float*)alloc((size_t)3072*4);
  float* xg_f = (float*)alloc((size_t)4096*1536*4);   // reused later as P_s (bf16 4096x3072)
  float* xg_b = (float*)alloc((size_t)4096*1536*4);   // reused later as P_e
  unsigned short* whh_bf = (unsigned short*)alloc((size_t)2*1536*384*2);
  unsigned int* hg = (unsigned int*)alloc((size_t)2*2*8*384*4);
  unsigned short* h_bf  = (unsigned short*)alloc((size_t)4096*768*2);
  unsigned short* sw1b  = (unsigned short*)alloc((size_t)3072*768*2);
  unsigned short* sw2b  = (unsigned short*)alloc((size_t)768*3072*2);
  unsigned short* ew1b  = (unsigned short*)alloc((size_t)3072*768*2);
  unsigned short* ew2b  = (unsigned short*)alloc((size_t)768*3072*2);
  unsigned short* ow1b  = (unsigned short*)alloc((size_t)3072*1536*2);
  unsigned short* ow2b  = (unsigned short*)alloc((size_t)768*3072*2);
  unsigned short* pw1b  = (unsigned short*)alloc((size_t)3072*768*2);
  unsigned short* pw2b  = (unsigned short*)alloc((size_t)768*3072*2);
  unsigned short* srep  = (unsigned short*)alloc((size_t)4096*768*2);
  unsigned short* erep  = (unsigned short*)alloc((size_t)4096*768*2);
  unsigned short* midb  = (unsigned short*)alloc((size_t)6144*3072*2);
  unsigned short* pe_bf = (unsigned short*)alloc((size_t)200*768*2);
  unsigned short* pmid  = (unsigned short*)alloc((size_t)200*3072*2);

  unsigned short* Ps = (unsigned short*)xg_f;   // 4096*3072*2 == 4096*1536*4
  unsigned short* Pe = (unsigned short*)xg_b;

  auto cast = [&](const float* s, unsigned short* d, size_t n){
    long n4 = (long)(n / 4);
    int grid = (int)((n4 + 255) / 256);
    k_cast_bf16<<<grid, 256, 0, stream>>>(s, d, n4);
  };

  hipMemsetAsync(hg, 0, (size_t)2*2*8*384*4, stream);
  hipMemsetAsync(zerob, 0, (size_t)3072*4, stream);

  cast(we, we_bf, (size_t)4096*768);
  cast(w_ih_f, wihf_bf, (size_t)1536*768);
  cast(w_ih_b, wihb_bf, (size_t)1536*768);
  cast(w_hh_f, whh_bf,               (size_t)1536*384);
  cast(w_hh_b, whh_bf + 1536*384,    (size_t)1536*384);
  cast(sw1, sw1b, (size_t)3072*768);  cast(sw2, sw2b, (size_t)768*3072);
  cast(ew1, ew1b, (size_t)3072*768);  cast(ew2, ew2b, (size_t)768*3072);
  cast(ow1, ow1b, (size_t)3072*1536); cast(ow2, ow2b, (size_t)768*3072);
  cast(pw1, pw1b, (size_t)3072*768);  cast(pw2, pw2b, (size_t)768*3072);
  cast(pe, pe_bf, (size_t)200*768);

  k_biascomb<<<6, 256, 0, stream>>>(b_ih_f, b_hh_f, bc_f, 1536);
  k_biascomb<<<6, 256, 0, stream>>>(b_ih_b, b_hh_b, bc_b, 1536);

  dim3 blk(256);
  // input-gate precompute (both biases folded in), fp32 out
  k_gemm2<0,0><<<dim3(12, 32), blk, 0, stream>>>(we_bf, wihf_bf, bc_f, xg_f, 4096, 1536, 768, 768);
  k_gemm2<0,0><<<dim3(12, 32), blk, 0, stream>>>(we_bf, wihb_bf, bc_b, xg_b, 4096, 1536, 768, 768);

  k_lstm3<<<12, 512, 0, stream>>>(xg_f, xg_b, whh_bf, mask, h_bf, hg);

  // start / end MLPs; ReLU of the cat is folded into the 2nd GEMM epilogue
  k_gemm2<1,1><<<dim3(24, 32), blk, 0, stream>>>(h_bf, sw1b, sb1, midb, 4096, 3072, 768, 768);
  k_gemm2<1,1><<<dim3( 6, 32), blk, 0, stream>>>(midb, sw2b, sb2, srep, 4096,  768, 3072, 3072);
  k_gemm2<1,1><<<dim3(24, 32), blk, 0, stream>>>(h_bf, ew1b, eb1, midb, 4096, 3072, 768, 768);
  k_gemm2<1,1><<<dim3( 6, 32), blk, 0, stream>>>(midb, ew2b, eb2, erep, 4096,  768, 3072, 3072);

  // P_s = relu(srep) @ Ws^T ; P_e = relu(erep) @ We^T   (Ws/We = ow1 halves, ldb=1536)
  k_gemm2<0,1><<<dim3(24, 32), blk, 0, stream>>>(srep, ow1b,       zerob, Ps, 4096, 3072, 768, 1536);
  k_gemm2<0,1><<<dim3(24, 32), blk, 0, stream>>>(erep, ow1b + 768, zerob, Pe, 4096, 3072, 768, 1536);

  float* outp = (float*)d_out;
  for (int b = 0; b < 8; b++){
    k_gadd<<<S_, 384, 0, stream>>>(Ps, Pe, sidx, ob1, b, midb);
    k_gemm2<0,0><<<dim3(6, 48), blk, 0, stream>>>(midb, ow2b, ob2,
                                                  outp + (size_t)b * S_ * H_, 6144, 768, 3072, 3072);
  }

  // prompt projection
  k_gemm2<1,1><<<dim3(24, 2), blk, 0, stream>>>(pe_bf, pw1b, pb1, pmid, 200, 3072, 768, 768);
  k_gemm2<0,0><<<dim3( 6, 2), blk, 0, stream>>>(pmid, pw2b, pb2,
                                                outp + (size_t)37748736, 200, 768, 3072, 3072);
}